// Round 11
// baseline (752.656 us; speedup 1.0000x reference)
//
#include <hip/hip_runtime.h>
#include <cstdint>
#include <cstddef>

typedef __attribute__((ext_vector_type(8))) short short8;
typedef __attribute__((ext_vector_type(4))) float f32x4;
typedef __attribute__((ext_vector_type(4))) int i32x4;
typedef __attribute__((ext_vector_type(8))) int i32x8;
typedef unsigned char u8;
typedef unsigned short u16;
typedef unsigned int u32;
typedef unsigned long long u64;

__device__ __forceinline__ u16 f2bf(float f) {
    u32 u = __float_as_uint(f);
    u = (u + 0x7FFFu + ((u >> 16) & 1u)) >> 16;
    return (u16)u;
}
__device__ __forceinline__ float bf2f(u16 h) {
    u32 u = ((u32)h) << 16;
    return __uint_as_float(u);
}
__device__ __forceinline__ u8 f2fp8(float f) {
    return (u8)(__builtin_amdgcn_cvt_pk_fp8_f32(f, f, 0, false) & 0xFF);
}

// async global -> LDS, 16B per lane. LDS dest is wave-uniform base + lane*16;
// global source IS per-lane -> swizzle the source, keep LDS linear.
__device__ __forceinline__ void gl_lds16(const void* g, void* l) {
    __builtin_amdgcn_global_load_lds((const __attribute__((address_space(1))) void*)g,
                                     (__attribute__((address_space(3))) void*)l, 16, 0, 0);
}

// ---------------------------------------------------------------------------
// Elementwise cast fp32 -> bf16 (vectorized x4). n must be multiple of 4.
__global__ void cast_bf16_kernel(const float* __restrict__ src, u16* __restrict__ dst) {
    int i = blockIdx.x * 256 + threadIdx.x;
    float4 v = *((const float4*)src + i);
    ushort4 r;
    r.x = f2bf(v.x); r.y = f2bf(v.y); r.z = f2bf(v.z); r.w = f2bf(v.w);
    *((ushort4*)dst + i) = r;
}

// ---------------------------------------------------------------------------
// Split fp32 -> (hi, lo) bf16 pair: hi = bf16(x), lo = bf16(x - fp32(hi)).
__global__ void split_bf16_kernel(const float* __restrict__ src,
                                  u16* __restrict__ hi, u16* __restrict__ lo) {
    int i = blockIdx.x * 256 + threadIdx.x;
    float4 v = *((const float4*)src + i);
    ushort4 h, l;
    h.x = f2bf(v.x); l.x = f2bf(v.x - bf2f(h.x));
    h.y = f2bf(v.y); l.y = f2bf(v.y - bf2f(h.y));
    h.z = f2bf(v.z); l.z = f2bf(v.z - bf2f(h.z));
    h.w = f2bf(v.w); l.w = f2bf(v.w - bf2f(h.w));
    *((ushort4*)hi + i) = h;
    *((ushort4*)lo + i) = l;
}

// ---------------------------------------------------------------------------
// Tiled transpose: src fp32 [R][C] -> dst bf16 [C][R]. grid=(C/32, R/32), block=256.
__global__ void cast_transpose_kernel(const float* __restrict__ src, u16* __restrict__ dst,
                                      int R, int C) {
    __shared__ float tile[32][33];
    int tx = threadIdx.x & 31, ty = threadIdx.x >> 5;
    int c0 = blockIdx.x * 32, r0 = blockIdx.y * 32;
#pragma unroll
    for (int j = 0; j < 4; j++)
        tile[ty + 8 * j][tx] = src[(size_t)(r0 + ty + 8 * j) * C + c0 + tx];
    __syncthreads();
#pragma unroll
    for (int j = 0; j < 4; j++)
        dst[(size_t)(c0 + ty + 8 * j) * R + r0 + tx] = f2bf(tile[tx][ty + 8 * j]);
}

// Tiled transpose: src fp32 [R][C] -> dst fp8 e4m3 [C][R]. (for V^T in PV pass)
__global__ void cast_transpose_fp8_kernel(const float* __restrict__ src, u8* __restrict__ dst,
                                          int R, int C) {
    __shared__ float tile[32][33];
    int tx = threadIdx.x & 31, ty = threadIdx.x >> 5;
    int c0 = blockIdx.x * 32, r0 = blockIdx.y * 32;
#pragma unroll
    for (int j = 0; j < 4; j++)
        tile[ty + 8 * j][tx] = src[(size_t)(r0 + ty + 8 * j) * C + c0 + tx];
    __syncthreads();
#pragma unroll
    for (int j = 0; j < 4; j++)
        dst[(size_t)(c0 + ty + 8 * j) * R + r0 + tx] = f2fp8(tile[tx][ty + 8 * j]);
}

// ---------------------------------------------------------------------------
// mem_keys -> mn_hi/mn_lo (split-bf16 row-normalized, B^T layout for sims MFMA)
// and Kb (bf16 raw, for attention).
__global__ __launch_bounds__(256) void key_prep_kernel(const float* __restrict__ mk,
                                                       u16* __restrict__ mn_hi,
                                                       u16* __restrict__ mn_lo,
                                                       u16* __restrict__ Kb) {
    int row = blockIdx.x, tid = threadIdx.x;
    const float* src = mk + (size_t)row * 512;
    float x0 = src[tid], x1 = src[tid + 256];
    float ss = x0 * x0 + x1 * x1;
#pragma unroll
    for (int m = 1; m < 64; m <<= 1) ss += __shfl_xor(ss, m);
    __shared__ float sred[4];
    if ((tid & 63) == 0) sred[tid >> 6] = ss;
    __syncthreads();
    float tot = sred[0] + sred[1] + sred[2] + sred[3];
    float inv = 1.0f / fmaxf(sqrtf(tot), 1e-8f);
    float n0 = x0 * inv, n1 = x1 * inv;
    u16 h0 = f2bf(n0), h1 = f2bf(n1);
    mn_hi[(size_t)row * 512 + tid] = h0;
    mn_hi[(size_t)row * 512 + tid + 256] = h1;
    mn_lo[(size_t)row * 512 + tid] = f2bf(n0 - bf2f(h0));
    mn_lo[(size_t)row * 512 + tid + 256] = f2bf(n1 - bf2f(h1));
    Kb[(size_t)row * 512 + tid] = f2bf(x0);
    Kb[(size_t)row * 512 + tid + 256] = f2bf(x1);
}

// ---------------------------------------------------------------------------
// GEMM: C[M,N] = A[M,K] * Bt[N,K]^T + bias[N].  bf16 inputs, fp32 accumulate.
// R4-PROVEN structure (BK=32): single-buffer, 2 barriers per K-step, gl_lds
// width-16 staging, 16B-segment XOR swizzle seg^=(row>>1)&3 on source+read.
// EPI==0: fp32 C row-major. EPI==1: q-proj permute -> Qatt bf16.
template <int BN, int EPI>
__global__ __launch_bounds__(256, 2) void gemm_bt_kernel(const u16* __restrict__ A,
                                                         const u16* __restrict__ Bt,
                                                         const float* __restrict__ bias,
                                                         void* __restrict__ Cout,
                                                         int M, int N, int K) {
    constexpr int NT = BN / 32;
    __shared__ __align__(16) u16 A_lds[128 * 32];
    __shared__ __align__(16) u16 B_lds[BN * 32];
    int tid = threadIdx.x;
    int w = tid >> 6, lane = tid & 63, l15 = lane & 15, quad = lane >> 4;
    int wm = w >> 1, wn = w & 1;
    int n0 = blockIdx.x * BN, m0 = blockIdx.y * 128;
    int sa = (l15 >> 1) & 3;

    f32x4 acc[4][NT];
#pragma unroll
    for (int i = 0; i < 4; i++)
#pragma unroll
        for (int j = 0; j < NT; j++) acc[i][j] = (f32x4)(0.0f);

    for (int kt = 0; kt < K; kt += 32) {
        __syncthreads();
#pragma unroll
        for (int i = 0; i < 2; i++) {
            int c = i * 256 + tid;
            int r = c >> 2, s = (c & 3) ^ ((r >> 1) & 3);
            gl_lds16(&A[(size_t)(m0 + r) * K + kt + s * 8], &A_lds[c * 8]);
        }
#pragma unroll
        for (int i = 0; i < BN / 64; i++) {
            int c = i * 256 + tid;
            int r = c >> 2, s = (c & 3) ^ ((r >> 1) & 3);
            gl_lds16(&Bt[(size_t)(n0 + r) * K + kt + s * 8], &B_lds[c * 8]);
        }
        __syncthreads();
        short8 af[4], bf[NT];
#pragma unroll
        for (int mt = 0; mt < 4; mt++)
            af[mt] = *(const short8*)&A_lds[(wm * 64 + mt * 16 + l15) * 32 + (quad ^ sa) * 8];
#pragma unroll
        for (int nt = 0; nt < NT; nt++)
            bf[nt] = *(const short8*)&B_lds[(wn * (BN / 2) + nt * 16 + l15) * 32 + (quad ^ sa) * 8];
#pragma unroll
        for (int mt = 0; mt < 4; mt++)
#pragma unroll
            for (int nt = 0; nt < NT; nt++)
                acc[mt][nt] = __builtin_amdgcn_mfma_f32_16x16x32_bf16(af[mt], bf[nt], acc[mt][nt], 0, 0, 0);
    }

#pragma unroll
    for (int nt = 0; nt < NT; nt++) {
        int col = n0 + wn * (BN / 2) + nt * 16 + l15;
        float bs = bias[col];
#pragma unroll
        for (int mt = 0; mt < 4; mt++) {
            int row = m0 + wm * 64 + mt * 16 + quad * 4;
#pragma unroll
            for (int r = 0; r < 4; r++) {
                float v = acc[mt][nt][r] + bs;
                if (EPI == 0) {
                    ((float*)Cout)[(size_t)(row + r) * N + col] = v;
                } else {
                    int rr = row + r;
                    int bi = rr >> 10, ni = rr & 1023;
                    int h = col >> 9, d = col & 511;
                    ((u16*)Cout)[(((size_t)((bi * 8 + h)) * 1024 + ni)) * 512 + d] = f2bf(v);
                }
            }
        }
    }
}

// ---------------------------------------------------------------------------
// BM=64 GEMM for out-proj: C[M,N] = A[M,K]*Bt[N,K]^T + bias. BN=64, BK=32.
// 512 blocks = 2 blocks/CU (vs 1 at BM=128) with zero extra memory traffic;
// co-resident blocks overlap each other's barrier drains. (R9-proven; the
// R10 XCD swizzle on top REGRESSED — grid is fully co-resident, chunked
// mapping thrashed per-XCD L2 with all 32 B-panels. Reverted.)
__global__ __launch_bounds__(256, 2) void gemm_bt_m64_kernel(const u16* __restrict__ A,
                                                             const u16* __restrict__ Bt,
                                                             const float* __restrict__ bias,
                                                             float* __restrict__ C,
                                                             int M, int N, int K) {
    __shared__ __align__(16) u16 A_lds[64 * 32];
    __shared__ __align__(16) u16 B_lds[64 * 32];
    int tid = threadIdx.x;
    int w = tid >> 6, lane = tid & 63, l15 = lane & 15, quad = lane >> 4;
    int wm = w >> 1, wn = w & 1;
    int n0 = blockIdx.x * 64, m0 = blockIdx.y * 64;
    int sa = (l15 >> 1) & 3;

    f32x4 acc[2][2];
#pragma unroll
    for (int i = 0; i < 2; i++)
#pragma unroll
        for (int j = 0; j < 2; j++) acc[i][j] = (f32x4)(0.0f);

    for (int kt = 0; kt < K; kt += 32) {
        __syncthreads();
        {
            int c = tid;
            int r = c >> 2, s = (c & 3) ^ ((r >> 1) & 3);
            gl_lds16(&A[(size_t)(m0 + r) * K + kt + s * 8], &A_lds[c * 8]);
            gl_lds16(&Bt[(size_t)(n0 + r) * K + kt + s * 8], &B_lds[c * 8]);
        }
        __syncthreads();
        short8 af[2], bf[2];
#pragma unroll
        for (int mt = 0; mt < 2; mt++)
            af[mt] = *(const short8*)&A_lds[(wm * 32 + mt * 16 + l15) * 32 + (quad ^ sa) * 8];
#pragma unroll
        for (int nt = 0; nt < 2; nt++)
            bf[nt] = *(const short8*)&B_lds[(wn * 32 + nt * 16 + l15) * 32 + (quad ^ sa) * 8];
#pragma unroll
        for (int mt = 0; mt < 2; mt++)
#pragma unroll
            for (int nt = 0; nt < 2; nt++)
                acc[mt][nt] = __builtin_amdgcn_mfma_f32_16x16x32_bf16(af[mt], bf[nt], acc[mt][nt], 0, 0, 0);
    }

#pragma unroll
    for (int nt = 0; nt < 2; nt++) {
        int col = n0 + wn * 32 + nt * 16 + l15;
        float bs = bias[col];
#pragma unroll
        for (int mt = 0; mt < 2; mt++) {
            int row = m0 + wm * 32 + mt * 16 + quad * 4;
#pragma unroll
            for (int r = 0; r < 4; r++)
                C[(size_t)(row + r) * N + col] = acc[mt][nt][r] + bs;
        }
    }
}

// ---------------------------------------------------------------------------
// S-pass (swapped operands -> S^T in acc): A = Kb (slots), B = Q (queries).
// BK=64 single-buffer (R6 proven: 181.9 us; R10's XCD swizzle regressed ->
// reverted). Lane owns 4 consecutive slots per acc reg -> in-lane fp8 pack,
// 2 shuffles per rowsum.
__global__ __launch_bounds__(256, 2) void s_exp_gemm_kernel(const u16* __restrict__ Q,
                                                            const u16* __restrict__ Kb,
                                                            u8* __restrict__ P,
                                                            float* __restrict__ denom) {
    __shared__ __align__(16) u16 A_lds[128 * 64];   // Kb slot rows
    __shared__ __align__(16) u16 B_lds[128 * 64];   // Q query rows
    int tid = threadIdx.x;
    int w = tid >> 6, lane = tid & 63, l15 = lane & 15, quad = lane >> 4;
    int wm = w >> 1, wn = w & 1;
    int s0 = blockIdx.x * 128, q0 = blockIdx.y * 128;

    f32x4 acc[4][4];
#pragma unroll
    for (int i = 0; i < 4; i++)
#pragma unroll
        for (int j = 0; j < 4; j++) acc[i][j] = (f32x4)(0.0f);

    for (int kt = 0; kt < 512; kt += 64) {
        __syncthreads();
#pragma unroll
        for (int i = 0; i < 4; i++) {
            int c = i * 256 + tid;
            int r = c >> 3, s = (c & 7) ^ (r & 7);
            gl_lds16(&Kb[(size_t)(s0 + r) * 512 + kt + s * 8], &A_lds[c * 8]);
            gl_lds16(&Q[(size_t)(q0 + r) * 512 + kt + s * 8], &B_lds[c * 8]);
        }
        __syncthreads();
#pragma unroll
        for (int kk = 0; kk < 2; kk++) {
            short8 af[4], bf[4];
#pragma unroll
            for (int mt = 0; mt < 4; mt++) {
                int row = wm * 64 + mt * 16 + l15;
                af[mt] = *(const short8*)&A_lds[row * 64 + (((kk * 4 + quad) ^ (row & 7)) * 8)];
            }
#pragma unroll
            for (int nt = 0; nt < 4; nt++) {
                int row = wn * 64 + nt * 16 + l15;
                bf[nt] = *(const short8*)&B_lds[row * 64 + (((kk * 4 + quad) ^ (row & 7)) * 8)];
            }
#pragma unroll
            for (int mt = 0; mt < 4; mt++)
#pragma unroll
                for (int nt = 0; nt < 4; nt++)
                    acc[mt][nt] = __builtin_amdgcn_mfma_f32_16x16x32_bf16(af[mt], bf[nt], acc[mt][nt], 0, 0, 0);
        }
    }

    const float sc = 0.06375871826463886f; // log2(e)/sqrt(512)
#pragma unroll
    for (int nt = 0; nt < 4; nt++) {
        int q = q0 + wn * 64 + nt * 16 + l15;     // query row (local to chunk)
        float rs = 0.f;
#pragma unroll
        for (int mt = 0; mt < 4; mt++) {
            float p0 = exp2f(acc[mt][nt][0] * sc);
            float p1 = exp2f(acc[mt][nt][1] * sc);
            float p2 = exp2f(acc[mt][nt][2] * sc);
            float p3 = exp2f(acc[mt][nt][3] * sc);
            rs += (p0 + p1) + (p2 + p3);
            u32 lo = (u32)__builtin_amdgcn_cvt_pk_fp8_f32(p0, p1, 0, false);
            u32 dw = (u32)__builtin_amdgcn_cvt_pk_fp8_f32(p2, p3, (int)lo, true);
            int col = s0 + wm * 64 + mt * 16 + quad * 4;   // 4 consecutive slots
            *(u32*)&P[(size_t)q * 4096 + col] = dw;
        }
        rs += __shfl_xor(rs, 16);
        rs += __shfl_xor(rs, 32);
        if (quad == 0) atomicAdd(&denom[q], rs);
    }
}

// ---------------------------------------------------------------------------
// PV-pass (MX-scaled fp8, unit scales): rv = (P * V) / denom. A = Vt8 (d),
// B = P (queries), K = 4096 slots. Single-buffer, BK=128, mfma_scale
// 16x16x128 (2x fp8 rate), 16B-seg swizzle seg^=(row&7).
// grid=(4 d-tiles, Mq/128 q-tiles): consecutive blocks share one P tile (L2).
__global__ __launch_bounds__(256, 2) void pv_gemm_kernel(const u8* __restrict__ P,
                                                         const u8* __restrict__ Vt8,
                                                         const float* __restrict__ denom,
                                                         u16* __restrict__ rv,
                                                         int bh0) {
    __shared__ __align__(16) u8 A_lds[128 * 128];  // Vt8 d rows
    __shared__ __align__(16) u8 B_lds[128 * 128];  // P query rows
    int tid = threadIdx.x;
    int w = tid >> 6, lane = tid & 63, l15 = lane & 15, quad = lane >> 4;
    int wm = w >> 1, wn = w & 1;
    int d0 = blockIdx.x * 128, q0 = blockIdx.y * 128;

    f32x4 acc[4][4];
#pragma unroll
    for (int i = 0; i < 4; i++)
#pragma unroll
        for (int j = 0; j < 4; j++) acc[i][j] = (f32x4)(0.0f);

    for (int kt = 0; kt < 4096; kt += 128) {
        __syncthreads();
#pragma unroll
        for (int i = 0; i < 4; i++) {
            int c = i * 256 + tid;
            int r = c >> 3, s = (c & 7) ^ (r & 7);
            gl_lds16(&Vt8[(size_t)(d0 + r) * 4096 + kt + s * 16], &A_lds[c * 16]);
            gl_lds16(&P[(size_t)(q0 + r) * 4096 + kt + s * 16], &B_lds[c * 16]);
        }
        __syncthreads();
        i32x8 af[4], bf[4];
#pragma unroll
        for (int mt = 0; mt < 4; mt++) {
            int row = wm * 64 + mt * 16 + l15;
            const u8* pa = &A_lds[row * 128];
            int sl0 = (quad * 2) ^ (row & 7), sl1 = (quad * 2 + 1) ^ (row & 7);
            i32x4 lo = *(const i32x4*)&pa[sl0 * 16];
            i32x4 hi = *(const i32x4*)&pa[sl1 * 16];
            af[mt] = __builtin_shufflevector(lo, hi, 0, 1, 2, 3, 4, 5, 6, 7);
        }
#pragma unroll
        for (int nt = 0; nt < 4; nt++) {
            int row = wn * 64 + nt * 16 + l15;
            const u8* pb = &B_lds[row * 128];
            int sl0 = (quad * 2) ^ (row & 7), sl1 = (quad * 2 + 1) ^ (row & 7);
            i32x4 lo = *(const i32x4*)&pb[sl0 * 16];
            i32x4 hi = *(const i32x4*)&pb[sl1 * 16];
            bf[nt] = __builtin_shufflevector(lo, hi, 0, 1, 2, 3, 4, 5, 6, 7);
        }
#pragma unroll
        for (int mt = 0; mt < 4; mt++)
#pragma unroll
            for (int nt = 0; nt < 4; nt++)
                acc[mt][nt] = __builtin_amdgcn_mfma_scale_f32_16x16x128_f8f6f4(
                    af[mt], bf[nt], acc[mt][nt], 0, 0,
                    0, 0x7F7F7F7F, 0, 0x7F7F7F7F);
    }

#pragma unroll
    for (int nt = 0; nt < 4; nt++) {
        int lq = q0 + wn * 64 + nt * 16 + l15;     // query row (local to chunk)
        int gr = bh0 * 1024 + lq;
        float inv = 1.0f / denom[lq];
        int b = gr >> 13, h = (gr >> 10) & 7, n = gr & 1023;
        size_t base = ((size_t)(b * 1024 + n)) * 4096 + h * 512;
#pragma unroll
        for (int mt = 0; mt < 4; mt++) {
            int d = d0 + wm * 64 + mt * 16 + quad * 4;   // 4 consecutive dims
            ushort4 v4;
            v4.x = f2bf(acc[mt][nt][0] * inv);
            v4.y = f2bf(acc[mt][nt][1] * inv);
            v4.z = f2bf(acc[mt][nt][2] * inv);
            v4.w = f2bf(acc[mt][nt][3] * inv);
            *(ushort4*)&rv[base + d] = v4;
        }
    }
}

// ---------------------------------------------------------------------------
// sims v3: MFMA GEMM with split-bf16 precision (plain bf16 would misrank).
// sims[wi][m] ~ wh.mh + wh.ml + wl.mh. grid=(32,8). Epilogue: per-row argmax
// keys (ties -> smaller m), atomicMax into amax.
__global__ __launch_bounds__(256, 2) void sims_mfma_kernel(const u16* __restrict__ Ah,
                                                           const u16* __restrict__ Al,
                                                           const u16* __restrict__ Bh,
                                                           const u16* __restrict__ Bl,
                                                           u64* __restrict__ amax) {
    __shared__ __align__(16) u16 Ah_lds[128 * 32];
    __shared__ __align__(16) u16 Al_lds[128 * 32];
    __shared__ __align__(16) u16 Bh_lds[128 * 32];
    __shared__ __align__(16) u16 Bl_lds[128 * 32];
    int tid = threadIdx.x;
    int w = tid >> 6, lane = tid & 63, l15 = lane & 15, quad = lane >> 4;
    int wm = w >> 1, wn = w & 1;
    int n0 = blockIdx.x * 128, m0 = blockIdx.y * 128;
    int sa = (l15 >> 1) & 3;

    f32x4 acc[4][4];
#pragma unroll
    for (int i = 0; i < 4; i++)
#pragma unroll
        for (int j = 0; j < 4; j++) acc[i][j] = (f32x4)(0.0f);

    for (int kt = 0; kt < 512; kt += 32) {
        __syncthreads();
#pragma unroll
        for (int i = 0; i < 2; i++) {
            int c = i * 256 + tid;
            int r = c >> 2, s = (c & 3) ^ ((r >> 1) & 3);
            size_t ga = (size_t)(m0 + r) * 512 + kt + s * 8;
            size_t gb = (size_t)(n0 + r) * 512 + kt + s * 8;
            gl_lds16(&Ah[ga], &Ah_lds[c * 8]);
            gl_lds16(&Al[ga], &Al_lds[c * 8]);
            gl_lds16(&Bh[gb], &Bh_lds[c * 8]);
            gl_lds16(&Bl[gb], &Bl_lds[c * 8]);
        }
        __syncthreads();
        short8 afh[4], afl[4], bfh[4], bfl[4];
#pragma unroll
        for (int mt = 0; mt < 4; mt++) {
            int off = (wm * 64 + mt * 16 + l15) * 32 + (quad ^ sa) * 8;
            afh[mt] = *(const short8*)&Ah_lds[off];
            afl[mt] = *(const short8*)&Al_lds[off];
        }
#pragma unroll
        for (int nt = 0; nt < 4; nt++) {
            int off = (wn * 64 + nt * 16 + l15) * 32 + (quad ^ sa) * 8;
            bfh[nt] = *(const short8*)&Bh_lds[off];
            bfl[nt] = *(const short8*)&Bl_lds[off];
        }
#pragma unroll
        for (int mt = 0; mt < 4; mt++)
#pragma unroll
            for (int nt = 0; nt < 4; nt++) {
                acc[mt][nt] = __builtin_amdgcn_mfma_f32_16x16x32_bf16(afh[mt], bfh[nt], acc[mt][nt], 0, 0, 0);
                acc[mt][nt] = __builtin_amdgcn_mfma_f32_16x16x32_bf16(afh[mt], bfl[nt], acc[mt][nt], 0, 0, 0);
                acc[mt][nt] = __builtin_amdgcn_mfma_f32_16x16x32_bf16(afl[mt], bfh[nt], acc[mt][nt], 0, 0, 0);
            }
    }

#pragma unroll
    for (int mt = 0; mt < 4; mt++) {
#pragma unroll
        for (int r = 0; r < 4; r++) {
            int row = m0 + wm * 64 + mt * 16 + quad * 4 + r;  // wi index
            u64 best = 0;
#pragma unroll
            for (int nt = 0; nt < 4; nt++) {
                int col = n0 + wn * 64 + nt * 16 + l15;       // slot index
                u32 bb = __float_as_uint(acc[mt][nt][r]);
                bb = (bb & 0x80000000u) ? ~bb : (bb | 0x80000000u);
                u64 key = ((u64)bb << 32) | (u32)(4095 - col);
                best = best > key ? best : key;
            }
            u64 o;
            o = __shfl_xor(best, 1); best = best > o ? best : o;
            o = __shfl_xor(best, 2); best = best > o ? best : o;
            o = __shfl_xor(best, 4); best = best > o ? best : o;
            o = __shfl_xor(best, 8); best = best > o ? best : o;
            if (l15 == 0) atomicMax(&amax[row], best);
        }
    }
}

// ---------------------------------------------------------------------------
// chains_build v2: decode idx, build per-slot chains. 16 blocks x 64 threads;
// scans over an LDS mirror of all 1024 decoded indices.
__global__ __launch_bounds__(64) void chains_build_kernel(const u64* __restrict__ amax,
                                                          int* __restrict__ idx,
                                                          int* __restrict__ nxt,
                                                          int* __restrict__ heads,
                                                          int* __restrict__ count) {
    __shared__ int sidx[1024];
    int tid = threadIdx.x;
    for (int j = tid; j < 1024; j += 64)
        sidx[j] = 4095 - (int)(u32)(amax[j] & 0xFFFFFFFFull);
    __syncthreads();
    int i = blockIdx.x * 64 + tid;
    int my = sidx[i];
    idx[i] = my;
    int nx = -1;
    for (int j = i + 1; j < 1024; j++)
        if (sidx[j] == my) { nx = j; break; }
    nxt[i] = nx;
    bool head = true;
    for (int j = 0; j < i; j++)
        if (sidx[j] == my) { head = false; break; }
    if (head) {
        int p = atomicAdd(count, 1);
        heads[p] = i;
    }
}

// ---------------------------------------------------------------------------
// G1[i][j] = write_keys[i] . Wg[0:512, j] + bg[j]   (fp32). 8 rows/block, grid=128.
__global__ __launch_bounds__(256) void g1_gemm_kernel(const float* __restrict__ wk,
                                                      const float* __restrict__ Wg,
                                                      const float* __restrict__ bg,
                                                      float* __restrict__ G1) {
    __shared__ float wkl[8][512];
    int tid = threadIdx.x;
    int i0 = blockIdx.x * 8;
    for (int i = tid; i < 8 * 512; i += 256) wkl[i >> 9][i & 511] = wk[(size_t)i0 * 512 + i];
    __syncthreads();
    float a0[8], a1[8];
#pragma unroll
    for (int i = 0; i < 8; i++) { a0[i] = 0.f; a1[i] = 0.f; }
    for (int c = 0; c < 512; c++) {
        float w0 = Wg[(size_t)c * 512 + tid];
        float w1 = Wg[(size_t)c * 512 + tid + 256];
#pragma unroll
        for (int ii = 0; ii < 8; ii++) {
            float s = wkl[ii][c];
            a0[ii] += s * w0; a1[ii] += s * w1;
        }
    }
    float b0 = bg[tid], b1 = bg[tid + 256];
#pragma unroll
    for (int ii = 0; ii < 8; ii++) {
        G1[(size_t)(i0 + ii) * 512 + tid] = a0[ii] + b0;
        G1[(size_t)(i0 + ii) * 512 + tid + 256] = a1[ii] + b1;
    }
}

// ---------------------------------------------------------------------------
// Apply per-slot chains sequentially (fp32). block = 256 threads per chain.
__global__ __launch_bounds__(256) void chain_apply_kernel(const int* __restrict__ heads,
                                                          const int* __restrict__ count,
                                                          const int* __restrict__ idx,
                                                          const int* __restrict__ nxt,
                                                          const float* __restrict__ G1,
                                                          const float* __restrict__ Wg,
                                                          const float* __restrict__ wk,
                                                          const float* __restrict__ wv,
                                                          const float* __restrict__ mk,
                                                          const float* __restrict__ mv,
                                                          float* __restrict__ outK,
                                                          float* __restrict__ outV) {
    int b = blockIdx.x;
    if (b >= *count) return;
    int i = heads[b];
    int s = idx[i];
    int tid = threadIdx.x;
    __shared__ float V[512];
    V[tid] = mv[(size_t)s * 512 + tid];
    V[tid + 256] = mv[(size_t)s * 512 + tid + 256];
    float k0 = mk[(size_t)s * 512 + tid], k1 = mk[(size_t)s * 512 + tid + 256];
    __syncthreads();
    while (i >= 0) {
        float a0 = G1[(size_t)i * 512 + tid], a1 = G1[(size_t)i * 512 + tid + 256];
        for (int c = 0; c < 512; c++) {
            float vc = V[c];
            a0 += vc * Wg[(size_t)(512 + c) * 512 + tid];
            a1 += vc * Wg[(size_t)(512 + c) * 512 + tid + 256];
        }
        float g0 = 1.f / (1.f + __expf(-a0));
        float g1 = 1.f / (1.f + __expf(-a1));
        __syncthreads(); // everyone finished reading V
        k0 = g0 * wk[(size_t)i * 512 + tid] + (1.f - g0) * k0;
        k1 = g1 * wk[(size_t)i * 512 + tid + 256] + (1.f - g1) * k1;
        V[tid] = g0 * wv[(size_t)i * 512 + tid] + (1.f - g0) * V[tid];
        V[tid + 256] = g1 * wv[(size_t)i * 512 + tid + 256] + (1.f - g1) * V[tid + 256];
        __syncthreads();
        i = nxt[i];
    }
    outK[(size_t)s * 512 + tid] = k0;
    outK[(size_t)s * 512 + tid + 256] = k1;
    outV[(size_t)s * 512 + tid] = V[tid];
    outV[(size_t)s * 512 + tid + 256] = V[tid + 256];
}

// ---------------------------------------------------------------------------
extern "C" void kernel_launch(void* const* d_in, const int* in_sizes, int n_in,
                              void* d_out, int out_size, void* d_ws, size_t ws_size,
                              hipStream_t stream) {
    const float* queries = (const float*)d_in[0]; // [4,1024,512]
    const float* wkeys   = (const float*)d_in[1]; // [1024,512]
    const float* wvals   = (const float*)d_in[2]; // [1024,512]
    const float* mkeys   = (const float*)d_in[3]; // [4096,512]
    const float* mvals   = (const float*)d_in[4]; // [4096,512]
    const float* Wq      = (const float*)d_in[5]; // [512,4096]
    const float* bq      = (const float*)d_in[6]; // [4096]
    const float* Wvp     = (const float*)d_in[7]; // [4096,512]
    const float* bvp     = (const float*)d_in[8]; // [512]
    const float* Wg      = (const float*)d_in[9]; // [1024,512]
    const float* bg      = (const float*)d_in[10];// [512]

    float* out_read = (float*)d_out;              // [4,1024,512]
    float* out_k = out_read + (size_t)4 * 1024 * 512; // [4096,512]
    float* out_v = out_k + (size_t)4096 * 512;        // [4096,512]

    char* ws = (char*)d_ws;
    const size_t MB = 1024 * 1024;
    // region [0, 4MB): Qbf during prep/q-proj, then reused for meta + denom
    u16* Qbf  = (u16*)(ws);            // 4 MB   queries bf16 [4096,512]
    u16* WqT  = (u16*)(ws + 4 * MB);   // 4 MB   Wq^T bf16 [4096,512]
    u16* Qatt = (u16*)(ws + 8 * MB);   // 32 MB  q bf16 [(b,h),n,d] = [32768,512]
    u16* Kb   = (u16*)(ws + 40 * MB);  // 4 MB   mem_keys bf16 [4096,512]
    u8*  Vt8  = (u8*)(ws + 44 * MB);   // 2 MB   mem_values^T fp8 [512,4096]
    u16* rv   = (u16*)(ws + 48 * MB);  // 32 MB  attention out bf16 [4096,4096]
    u16* WvpT = (u16*)(ws + 80 * MB);  // 4 MB   Wvp^T bf16 [512,4096]
    // write-path buffers (dead before attention's P overlay):
    u16* mn_hi = (u16*)(ws + 84 * MB); // 4 MB  normalized keys hi bf16 [4096,512]
    u16* mn_lo = (u16*)(ws + 88 * MB); // 4 MB  normalized keys lo bf16 [4096,512]
    float* G1  = (float*)(ws + 92 * MB); // 2 MB gate pre from write_keys [1024,512]
    u16* wk_hi = (u16*)(ws + 94 * MB); // 1 MB  write_keys hi bf16 [1024,512]
    u16* wk_lo = (u16*)(ws + 95 * MB); // 1 MB  write_keys lo bf16 [1024,512]
    // meta + denom overlay the dead Qbf region (valid after q-proj completes)
    u64* amax   = (u64*)(ws);                   // 8 KB
    int* count  = (int*)(ws + 8192);            // 4 B
    int* idx    = (int*)(ws + 8192 + 256);      // 4 KB
    int* nxt    = (int*)(ws + 8192 + 256 + 4096);   // 4 KB
    int* heads  = (int*)(ws + 8192 + 256 + 8192);   // 4 KB
    float* denom = (float*)(ws + 32 * 1024);    // 128 KB [32768]
    // P (fp8) overlays the dead write-path region (valid after chain_apply)
    u8* P = (u8*)(ws + 84 * MB);                // up to 128 MB [G*1024, 4096]
    (void)in_sizes; (void)n_in; (void)out_size;

    // chunk size over bh: P needs G*4MB (fp8) starting at 84MB
    size_t avail = (ws_size > 84 * MB) ? ws_size - 84 * MB : 0;
    int G = 2; // proven-safe floor
    for (int g = 32; g >= 2; g >>= 1)
        if ((size_t)g * 4 * MB <= avail) { G = g; break; }

    // new_keys / new_values start as copies of mem_keys / mem_values
    hipMemcpyAsync(out_k, mkeys, (size_t)4096 * 512 * 4, hipMemcpyDeviceToDevice, stream);
    hipMemcpyAsync(out_v, mvals, (size_t)4096 * 512 * 4, hipMemcpyDeviceToDevice, stream);

    // ---- prep casts / transposes ----
    cast_bf16_kernel<<<2048, 256, 0, stream>>>(queries, Qbf);
    cast_transpose_kernel<<<dim3(4096 / 32, 512 / 32), 256, 0, stream>>>(Wq, WqT, 512, 4096);
    cast_transpose_kernel<<<dim3(512 / 32, 4096 / 32), 256, 0, stream>>>(Wvp, WvpT, 4096, 512);
    cast_transpose_fp8_kernel<<<dim3(512 / 32, 4096 / 32), 256, 0, stream>>>(mvals, Vt8, 4096, 512);
    key_prep_kernel<<<4096, 256, 0, stream>>>(mkeys, mn_hi, mn_lo, Kb);
    split_bf16_kernel<<<512, 256, 0, stream>>>(wkeys, wk_hi, wk_lo);

    // ---- q-proj (last user of Qbf/WqT) ----
    gemm_bt_kernel<128, 1><<<dim3(32, 32), 256, 0, stream>>>(Qbf, WqT, bq, (void*)Qatt, 4096, 4096, 512);

    // ---- write path (fp32-accurate), frees buffers for the P overlay after ----
    hipMemsetAsync(ws, 0, 8192 + 256, stream);          // amax + count (Qbf now dead)
    hipMemsetAsync(denom, 0, 32768 * 4, stream);        // denom
    sims_mfma_kernel<<<dim3(32, 8), 256, 0, stream>>>(wk_hi, wk_lo, mn_hi, mn_lo, amax);
    chains_build_kernel<<<16, 64, 0, stream>>>(amax, idx, nxt, heads, count);
    g1_gemm_kernel<<<128, 256, 0, stream>>>(wkeys, Wg, bg, G1);
    chain_apply_kernel<<<1024, 256, 0, stream>>>(heads, count, idx, nxt, G1, Wg,
                                                 wkeys, wvals, mkeys, mvals, out_k, out_v);

    // ---- attention as two GEMM passes (P in fp8), chunked over bh ----
    for (int bh0 = 0; bh0 < 32; bh0 += G) {
        const u16* Achunk = Qatt + (size_t)bh0 * 1024 * 512;
        float* dchunk = denom + bh0 * 1024;
        s_exp_gemm_kernel<<<dim3(32, G * 8), 256, 0, stream>>>(Achunk, Kb, P, dchunk);
        pv_gemm_kernel<<<dim3(4, G * 8), 256, 0, stream>>>(P, Vt8, dchunk, rv, bh0);
    }

    // ---- out-proj: BM=64 tile, 2 blocks/CU ----
    gemm_bt_m64_kernel<<<dim3(8, 64), 256, 0, stream>>>(rv, WvpT, bvp, out_read, 4096, 512, 4096);
}

// Round 12
// 706.555 us; speedup vs baseline: 1.0652x; 1.0652x over previous
//
#include <hip/hip_runtime.h>
#include <cstdint>
#include <cstddef>

typedef __attribute__((ext_vector_type(8))) short short8;
typedef __attribute__((ext_vector_type(4))) float f32x4;
typedef __attribute__((ext_vector_type(4))) int i32x4;
typedef __attribute__((ext_vector_type(8))) int i32x8;
typedef unsigned char u8;
typedef unsigned short u16;
typedef unsigned int u32;
typedef unsigned long long u64;

__device__ __forceinline__ u16 f2bf(float f) {
    u32 u = __float_as_uint(f);
    u = (u + 0x7FFFu + ((u >> 16) & 1u)) >> 16;
    return (u16)u;
}
__device__ __forceinline__ float bf2f(u16 h) {
    u32 u = ((u32)h) << 16;
    return __uint_as_float(u);
}
__device__ __forceinline__ u8 f2fp8(float f) {
    return (u8)(__builtin_amdgcn_cvt_pk_fp8_f32(f, f, 0, false) & 0xFF);
}

// async global -> LDS, 16B per lane. LDS dest is wave-uniform base + lane*16;
// global source IS per-lane -> swizzle the source, keep LDS linear.
__device__ __forceinline__ void gl_lds16(const void* g, void* l) {
    __builtin_amdgcn_global_load_lds((const __attribute__((address_space(1))) void*)g,
                                     (__attribute__((address_space(3))) void*)l, 16, 0, 0);
}

// ---------------------------------------------------------------------------
// Elementwise cast fp32 -> bf16 (vectorized x4). n must be multiple of 4.
__global__ void cast_bf16_kernel(const float* __restrict__ src, u16* __restrict__ dst) {
    int i = blockIdx.x * 256 + threadIdx.x;
    float4 v = *((const float4*)src + i);
    ushort4 r;
    r.x = f2bf(v.x); r.y = f2bf(v.y); r.z = f2bf(v.z); r.w = f2bf(v.w);
    *((ushort4*)dst + i) = r;
}

// ---------------------------------------------------------------------------
// Split fp32 -> (hi, lo) bf16 pair: hi = bf16(x), lo = bf16(x - fp32(hi)).
__global__ void split_bf16_kernel(const float* __restrict__ src,
                                  u16* __restrict__ hi, u16* __restrict__ lo) {
    int i = blockIdx.x * 256 + threadIdx.x;
    float4 v = *((const float4*)src + i);
    ushort4 h, l;
    h.x = f2bf(v.x); l.x = f2bf(v.x - bf2f(h.x));
    h.y = f2bf(v.y); l.y = f2bf(v.y - bf2f(h.y));
    h.z = f2bf(v.z); l.z = f2bf(v.z - bf2f(h.z));
    h.w = f2bf(v.w); l.w = f2bf(v.w - bf2f(h.w));
    *((ushort4*)hi + i) = h;
    *((ushort4*)lo + i) = l;
}

// ---------------------------------------------------------------------------
// Tiled transpose: src fp32 [R][C] -> dst bf16 [C][R]. grid=(C/32, R/32), block=256.
__global__ void cast_transpose_kernel(const float* __restrict__ src, u16* __restrict__ dst,
                                      int R, int C) {
    __shared__ float tile[32][33];
    int tx = threadIdx.x & 31, ty = threadIdx.x >> 5;
    int c0 = blockIdx.x * 32, r0 = blockIdx.y * 32;
#pragma unroll
    for (int j = 0; j < 4; j++)
        tile[ty + 8 * j][tx] = src[(size_t)(r0 + ty + 8 * j) * C + c0 + tx];
    __syncthreads();
#pragma unroll
    for (int j = 0; j < 4; j++)
        dst[(size_t)(c0 + ty + 8 * j) * R + r0 + tx] = f2bf(tile[tx][ty + 8 * j]);
}

// Tiled transpose: src fp32 [R][C] -> dst fp8 e4m3 [C][R]. (for V^T in PV pass)
__global__ void cast_transpose_fp8_kernel(const float* __restrict__ src, u8* __restrict__ dst,
                                          int R, int C) {
    __shared__ float tile[32][33];
    int tx = threadIdx.x & 31, ty = threadIdx.x >> 5;
    int c0 = blockIdx.x * 32, r0 = blockIdx.y * 32;
#pragma unroll
    for (int j = 0; j < 4; j++)
        tile[ty + 8 * j][tx] = src[(size_t)(r0 + ty + 8 * j) * C + c0 + tx];
    __syncthreads();
#pragma unroll
    for (int j = 0; j < 4; j++)
        dst[(size_t)(c0 + ty + 8 * j) * R + r0 + tx] = f2fp8(tile[tx][ty + 8 * j]);
}

// ---------------------------------------------------------------------------
// mem_keys -> mn_hi/mn_lo (split-bf16 row-normalized, B^T layout for sims MFMA)
// and Kb (bf16 raw, for attention).
__global__ __launch_bounds__(256) void key_prep_kernel(const float* __restrict__ mk,
                                                       u16* __restrict__ mn_hi,
                                                       u16* __restrict__ mn_lo,
                                                       u16* __restrict__ Kb) {
    int row = blockIdx.x, tid = threadIdx.x;
    const float* src = mk + (size_t)row * 512;
    float x0 = src[tid], x1 = src[tid + 256];
    float ss = x0 * x0 + x1 * x1;
#pragma unroll
    for (int m = 1; m < 64; m <<= 1) ss += __shfl_xor(ss, m);
    __shared__ float sred[4];
    if ((tid & 63) == 0) sred[tid >> 6] = ss;
    __syncthreads();
    float tot = sred[0] + sred[1] + sred[2] + sred[3];
    float inv = 1.0f / fmaxf(sqrtf(tot), 1e-8f);
    float n0 = x0 * inv, n1 = x1 * inv;
    u16 h0 = f2bf(n0), h1 = f2bf(n1);
    mn_hi[(size_t)row * 512 + tid] = h0;
    mn_hi[(size_t)row * 512 + tid + 256] = h1;
    mn_lo[(size_t)row * 512 + tid] = f2bf(n0 - bf2f(h0));
    mn_lo[(size_t)row * 512 + tid + 256] = f2bf(n1 - bf2f(h1));
    Kb[(size_t)row * 512 + tid] = f2bf(x0);
    Kb[(size_t)row * 512 + tid + 256] = f2bf(x1);
}

// ---------------------------------------------------------------------------
// GEMM: C[M,N] = A[M,K] * Bt[N,K]^T + bias[N].  bf16 inputs, fp32 accumulate.
// R4-PROVEN structure (BK=32): single-buffer, 2 barriers per K-step, gl_lds
// width-16 staging, 16B-segment XOR swizzle seg^=(row>>1)&3 on source+read.
// EPI==0: fp32 C row-major. EPI==1: q-proj permute -> Qatt bf16.
template <int BN, int EPI>
__global__ __launch_bounds__(256, 2) void gemm_bt_kernel(const u16* __restrict__ A,
                                                         const u16* __restrict__ Bt,
                                                         const float* __restrict__ bias,
                                                         void* __restrict__ Cout,
                                                         int M, int N, int K) {
    constexpr int NT = BN / 32;
    __shared__ __align__(16) u16 A_lds[128 * 32];
    __shared__ __align__(16) u16 B_lds[BN * 32];
    int tid = threadIdx.x;
    int w = tid >> 6, lane = tid & 63, l15 = lane & 15, quad = lane >> 4;
    int wm = w >> 1, wn = w & 1;
    int n0 = blockIdx.x * BN, m0 = blockIdx.y * 128;
    int sa = (l15 >> 1) & 3;

    f32x4 acc[4][NT];
#pragma unroll
    for (int i = 0; i < 4; i++)
#pragma unroll
        for (int j = 0; j < NT; j++) acc[i][j] = (f32x4)(0.0f);

    for (int kt = 0; kt < K; kt += 32) {
        __syncthreads();
#pragma unroll
        for (int i = 0; i < 2; i++) {
            int c = i * 256 + tid;
            int r = c >> 2, s = (c & 3) ^ ((r >> 1) & 3);
            gl_lds16(&A[(size_t)(m0 + r) * K + kt + s * 8], &A_lds[c * 8]);
        }
#pragma unroll
        for (int i = 0; i < BN / 64; i++) {
            int c = i * 256 + tid;
            int r = c >> 2, s = (c & 3) ^ ((r >> 1) & 3);
            gl_lds16(&Bt[(size_t)(n0 + r) * K + kt + s * 8], &B_lds[c * 8]);
        }
        __syncthreads();
        short8 af[4], bf[NT];
#pragma unroll
        for (int mt = 0; mt < 4; mt++)
            af[mt] = *(const short8*)&A_lds[(wm * 64 + mt * 16 + l15) * 32 + (quad ^ sa) * 8];
#pragma unroll
        for (int nt = 0; nt < NT; nt++)
            bf[nt] = *(const short8*)&B_lds[(wn * (BN / 2) + nt * 16 + l15) * 32 + (quad ^ sa) * 8];
#pragma unroll
        for (int mt = 0; mt < 4; mt++)
#pragma unroll
            for (int nt = 0; nt < NT; nt++)
                acc[mt][nt] = __builtin_amdgcn_mfma_f32_16x16x32_bf16(af[mt], bf[nt], acc[mt][nt], 0, 0, 0);
    }

#pragma unroll
    for (int nt = 0; nt < NT; nt++) {
        int col = n0 + wn * (BN / 2) + nt * 16 + l15;
        float bs = bias[col];
#pragma unroll
        for (int mt = 0; mt < 4; mt++) {
            int row = m0 + wm * 64 + mt * 16 + quad * 4;
#pragma unroll
            for (int r = 0; r < 4; r++) {
                float v = acc[mt][nt][r] + bs;
                if (EPI == 0) {
                    ((float*)Cout)[(size_t)(row + r) * N + col] = v;
                } else {
                    int rr = row + r;
                    int bi = rr >> 10, ni = rr & 1023;
                    int h = col >> 9, d = col & 511;
                    ((u16*)Cout)[(((size_t)((bi * 8 + h)) * 1024 + ni)) * 512 + d] = f2bf(v);
                }
            }
        }
    }
}

// ---------------------------------------------------------------------------
// BM=64 GEMM for out-proj: C[M,N] = A[M,K]*Bt[N,K]^T + bias. BN=64, BK=32.
// 512 blocks = 2 blocks/CU (vs 1 at BM=128) with zero extra memory traffic;
// co-resident blocks overlap each other's barrier drains. (R9-proven.)
__global__ __launch_bounds__(256, 2) void gemm_bt_m64_kernel(const u16* __restrict__ A,
                                                             const u16* __restrict__ Bt,
                                                             const float* __restrict__ bias,
                                                             float* __restrict__ C,
                                                             int M, int N, int K) {
    __shared__ __align__(16) u16 A_lds[64 * 32];
    __shared__ __align__(16) u16 B_lds[64 * 32];
    int tid = threadIdx.x;
    int w = tid >> 6, lane = tid & 63, l15 = lane & 15, quad = lane >> 4;
    int wm = w >> 1, wn = w & 1;
    int n0 = blockIdx.x * 64, m0 = blockIdx.y * 64;
    int sa = (l15 >> 1) & 3;

    f32x4 acc[2][2];
#pragma unroll
    for (int i = 0; i < 2; i++)
#pragma unroll
        for (int j = 0; j < 2; j++) acc[i][j] = (f32x4)(0.0f);

    for (int kt = 0; kt < K; kt += 32) {
        __syncthreads();
        {
            int c = tid;
            int r = c >> 2, s = (c & 3) ^ ((r >> 1) & 3);
            gl_lds16(&A[(size_t)(m0 + r) * K + kt + s * 8], &A_lds[c * 8]);
            gl_lds16(&Bt[(size_t)(n0 + r) * K + kt + s * 8], &B_lds[c * 8]);
        }
        __syncthreads();
        short8 af[2], bf[2];
#pragma unroll
        for (int mt = 0; mt < 2; mt++)
            af[mt] = *(const short8*)&A_lds[(wm * 32 + mt * 16 + l15) * 32 + (quad ^ sa) * 8];
#pragma unroll
        for (int nt = 0; nt < 2; nt++)
            bf[nt] = *(const short8*)&B_lds[(wn * 32 + nt * 16 + l15) * 32 + (quad ^ sa) * 8];
#pragma unroll
        for (int mt = 0; mt < 2; mt++)
#pragma unroll
            for (int nt = 0; nt < 2; nt++)
                acc[mt][nt] = __builtin_amdgcn_mfma_f32_16x16x32_bf16(af[mt], bf[nt], acc[mt][nt], 0, 0, 0);
    }

#pragma unroll
    for (int nt = 0; nt < 2; nt++) {
        int col = n0 + wn * 32 + nt * 16 + l15;
        float bs = bias[col];
#pragma unroll
        for (int mt = 0; mt < 2; mt++) {
            int row = m0 + wm * 32 + mt * 16 + quad * 4;
#pragma unroll
            for (int r = 0; r < 4; r++)
                C[(size_t)(row + r) * N + col] = acc[mt][nt][r] + bs;
        }
    }
}

// ---------------------------------------------------------------------------
// S-pass (swapped operands -> S^T in acc): A = Kb (slots), B = Q (queries).
// BK=64 single-buffer (R6 proven). Lane owns 4 consecutive slots per acc reg
// -> in-lane fp8 pack, 2 shuffles per rowsum.
__global__ __launch_bounds__(256, 2) void s_exp_gemm_kernel(const u16* __restrict__ Q,
                                                            const u16* __restrict__ Kb,
                                                            u8* __restrict__ P,
                                                            float* __restrict__ denom) {
    __shared__ __align__(16) u16 A_lds[128 * 64];   // Kb slot rows
    __shared__ __align__(16) u16 B_lds[128 * 64];   // Q query rows
    int tid = threadIdx.x;
    int w = tid >> 6, lane = tid & 63, l15 = lane & 15, quad = lane >> 4;
    int wm = w >> 1, wn = w & 1;
    int s0 = blockIdx.x * 128, q0 = blockIdx.y * 128;

    f32x4 acc[4][4];
#pragma unroll
    for (int i = 0; i < 4; i++)
#pragma unroll
        for (int j = 0; j < 4; j++) acc[i][j] = (f32x4)(0.0f);

    for (int kt = 0; kt < 512; kt += 64) {
        __syncthreads();
#pragma unroll
        for (int i = 0; i < 4; i++) {
            int c = i * 256 + tid;
            int r = c >> 3, s = (c & 7) ^ (r & 7);
            gl_lds16(&Kb[(size_t)(s0 + r) * 512 + kt + s * 8], &A_lds[c * 8]);
            gl_lds16(&Q[(size_t)(q0 + r) * 512 + kt + s * 8], &B_lds[c * 8]);
        }
        __syncthreads();
#pragma unroll
        for (int kk = 0; kk < 2; kk++) {
            short8 af[4], bf[4];
#pragma unroll
            for (int mt = 0; mt < 4; mt++) {
                int row = wm * 64 + mt * 16 + l15;
                af[mt] = *(const short8*)&A_lds[row * 64 + (((kk * 4 + quad) ^ (row & 7)) * 8)];
            }
#pragma unroll
            for (int nt = 0; nt < 4; nt++) {
                int row = wn * 64 + nt * 16 + l15;
                bf[nt] = *(const short8*)&B_lds[row * 64 + (((kk * 4 + quad) ^ (row & 7)) * 8)];
            }
#pragma unroll
            for (int mt = 0; mt < 4; mt++)
#pragma unroll
                for (int nt = 0; nt < 4; nt++)
                    acc[mt][nt] = __builtin_amdgcn_mfma_f32_16x16x32_bf16(af[mt], bf[nt], acc[mt][nt], 0, 0, 0);
        }
    }

    const float sc = 0.06375871826463886f; // log2(e)/sqrt(512)
#pragma unroll
    for (int nt = 0; nt < 4; nt++) {
        int q = q0 + wn * 64 + nt * 16 + l15;     // query row (local to chunk)
        float rs = 0.f;
#pragma unroll
        for (int mt = 0; mt < 4; mt++) {
            float p0 = exp2f(acc[mt][nt][0] * sc);
            float p1 = exp2f(acc[mt][nt][1] * sc);
            float p2 = exp2f(acc[mt][nt][2] * sc);
            float p3 = exp2f(acc[mt][nt][3] * sc);
            rs += (p0 + p1) + (p2 + p3);
            u32 lo = (u32)__builtin_amdgcn_cvt_pk_fp8_f32(p0, p1, 0, false);
            u32 dw = (u32)__builtin_amdgcn_cvt_pk_fp8_f32(p2, p3, (int)lo, true);
            int col = s0 + wm * 64 + mt * 16 + quad * 4;   // 4 consecutive slots
            *(u32*)&P[(size_t)q * 4096 + col] = dw;
        }
        rs += __shfl_xor(rs, 16);
        rs += __shfl_xor(rs, 32);
        if (quad == 0) atomicAdd(&denom[q], rs);
    }
}

// ---------------------------------------------------------------------------
// PV-pass (MX-scaled fp8, unit scales): rv = (P * V) / denom. A = Vt8 (d),
// B = P (queries), K = 4096 slots. Single-buffer, BK=128, mfma_scale
// 16x16x128 (2x fp8 rate), 16B-seg swizzle seg^=(row&7).
// grid=(4 d-tiles, Mq/128 q-tiles): consecutive blocks share one P tile (L2).
__global__ __launch_bounds__(256, 2) void pv_gemm_kernel(const u8* __restrict__ P,
                                                         const u8* __restrict__ Vt8,
                                                         const float* __restrict__ denom,
                                                         u16* __restrict__ rv,
                                                         int bh0) {
    __shared__ __align__(16) u8 A_lds[128 * 128];  // Vt8 d rows
    __shared__ __align__(16) u8 B_lds[128 * 128];  // P query rows
    int tid = threadIdx.x;
    int w = tid >> 6, lane = tid & 63, l15 = lane & 15, quad = lane >> 4;
    int wm = w >> 1, wn = w & 1;
    int d0 = blockIdx.x * 128, q0 = blockIdx.y * 128;

    f32x4 acc[4][4];
#pragma unroll
    for (int i = 0; i < 4; i++)
#pragma unroll
        for (int j = 0; j < 4; j++) acc[i][j] = (f32x4)(0.0f);

    for (int kt = 0; kt < 4096; kt += 128) {
        __syncthreads();
#pragma unroll
        for (int i = 0; i < 4; i++) {
            int c = i * 256 + tid;
            int r = c >> 3, s = (c & 7) ^ (r & 7);
            gl_lds16(&Vt8[(size_t)(d0 + r) * 4096 + kt + s * 16], &A_lds[c * 16]);
            gl_lds16(&P[(size_t)(q0 + r) * 4096 + kt + s * 16], &B_lds[c * 16]);
        }
        __syncthreads();
        i32x8 af[4], bf[4];
#pragma unroll
        for (int mt = 0; mt < 4; mt++) {
            int row = wm * 64 + mt * 16 + l15;
            const u8* pa = &A_lds[row * 128];
            int sl0 = (quad * 2) ^ (row & 7), sl1 = (quad * 2 + 1) ^ (row & 7);
            i32x4 lo = *(const i32x4*)&pa[sl0 * 16];
            i32x4 hi = *(const i32x4*)&pa[sl1 * 16];
            af[mt] = __builtin_shufflevector(lo, hi, 0, 1, 2, 3, 4, 5, 6, 7);
        }
#pragma unroll
        for (int nt = 0; nt < 4; nt++) {
            int row = wn * 64 + nt * 16 + l15;
            const u8* pb = &B_lds[row * 128];
            int sl0 = (quad * 2) ^ (row & 7), sl1 = (quad * 2 + 1) ^ (row & 7);
            i32x4 lo = *(const i32x4*)&pb[sl0 * 16];
            i32x4 hi = *(const i32x4*)&pb[sl1 * 16];
            bf[nt] = __builtin_shufflevector(lo, hi, 0, 1, 2, 3, 4, 5, 6, 7);
        }
#pragma unroll
        for (int mt = 0; mt < 4; mt++)
#pragma unroll
            for (int nt = 0; nt < 4; nt++)
                acc[mt][nt] = __builtin_amdgcn_mfma_scale_f32_16x16x128_f8f6f4(
                    af[mt], bf[nt], acc[mt][nt], 0, 0,
                    0, 0x7F7F7F7F, 0, 0x7F7F7F7F);
    }

#pragma unroll
    for (int nt = 0; nt < 4; nt++) {
        int lq = q0 + wn * 64 + nt * 16 + l15;     // query row (local to chunk)
        int gr = bh0 * 1024 + lq;
        float inv = 1.0f / denom[lq];
        int b = gr >> 13, h = (gr >> 10) & 7, n = gr & 1023;
        size_t base = ((size_t)(b * 1024 + n)) * 4096 + h * 512;
#pragma unroll
        for (int mt = 0; mt < 4; mt++) {
            int d = d0 + wm * 64 + mt * 16 + quad * 4;   // 4 consecutive dims
            ushort4 v4;
            v4.x = f2bf(acc[mt][nt][0] * inv);
            v4.y = f2bf(acc[mt][nt][1] * inv);
            v4.z = f2bf(acc[mt][nt][2] * inv);
            v4.w = f2bf(acc[mt][nt][3] * inv);
            *(ushort4*)&rv[base + d] = v4;
        }
    }
}

// ---------------------------------------------------------------------------
// sims v3: MFMA GEMM with split-bf16 precision (plain bf16 would misrank).
// sims[wi][m] ~ wh.mh + wh.ml + wl.mh. grid=(32,8). Epilogue: per-row argmax
// keys (ties -> smaller m), atomicMax into amax.
__global__ __launch_bounds__(256, 2) void sims_mfma_kernel(const u16* __restrict__ Ah,
                                                           const u16* __restrict__ Al,
                                                           const u16* __restrict__ Bh,
                                                           const u16* __restrict__ Bl,
                                                           u64* __restrict__ amax) {
    __shared__ __align__(16) u16 Ah_lds[128 * 32];
    __shared__ __align__(16) u16 Al_lds[128 * 32];
    __shared__ __align__(16) u16 Bh_lds[128 * 32];
    __shared__ __align__(16) u16 Bl_lds[128 * 32];
    int tid = threadIdx.x;
    int w = tid >> 6, lane = tid & 63, l15 = lane & 15, quad = lane >> 4;
    int wm = w >> 1, wn = w & 1;
    int n0 = blockIdx.x * 128, m0 = blockIdx.y * 128;
    int sa = (l15 >> 1) & 3;

    f32x4 acc[4][4];
#pragma unroll
    for (int i = 0; i < 4; i++)
#pragma unroll
        for (int j = 0; j < 4; j++) acc[i][j] = (f32x4)(0.0f);

    for (int kt = 0; kt < 512; kt += 32) {
        __syncthreads();
#pragma unroll
        for (int i = 0; i < 2; i++) {
            int c = i * 256 + tid;
            int r = c >> 2, s = (c & 3) ^ ((r >> 1) & 3);
            size_t ga = (size_t)(m0 + r) * 512 + kt + s * 8;
            size_t gb = (size_t)(n0 + r) * 512 + kt + s * 8;
            gl_lds16(&Ah[ga], &Ah_lds[c * 8]);
            gl_lds16(&Al[ga], &Al_lds[c * 8]);
            gl_lds16(&Bh[gb], &Bh_lds[c * 8]);
            gl_lds16(&Bl[gb], &Bl_lds[c * 8]);
        }
        __syncthreads();
        short8 afh[4], afl[4], bfh[4], bfl[4];
#pragma unroll
        for (int mt = 0; mt < 4; mt++) {
            int off = (wm * 64 + mt * 16 + l15) * 32 + (quad ^ sa) * 8;
            afh[mt] = *(const short8*)&Ah_lds[off];
            afl[mt] = *(const short8*)&Al_lds[off];
        }
#pragma unroll
        for (int nt = 0; nt < 4; nt++) {
            int off = (wn * 64 + nt * 16 + l15) * 32 + (quad ^ sa) * 8;
            bfh[nt] = *(const short8*)&Bh_lds[off];
            bfl[nt] = *(const short8*)&Bl_lds[off];
        }
#pragma unroll
        for (int mt = 0; mt < 4; mt++)
#pragma unroll
            for (int nt = 0; nt < 4; nt++) {
                acc[mt][nt] = __builtin_amdgcn_mfma_f32_16x16x32_bf16(afh[mt], bfh[nt], acc[mt][nt], 0, 0, 0);
                acc[mt][nt] = __builtin_amdgcn_mfma_f32_16x16x32_bf16(afh[mt], bfl[nt], acc[mt][nt], 0, 0, 0);
                acc[mt][nt] = __builtin_amdgcn_mfma_f32_16x16x32_bf16(afl[mt], bfh[nt], acc[mt][nt], 0, 0, 0);
            }
    }

#pragma unroll
    for (int mt = 0; mt < 4; mt++) {
#pragma unroll
        for (int r = 0; r < 4; r++) {
            int row = m0 + wm * 64 + mt * 16 + quad * 4 + r;  // wi index
            u64 best = 0;
#pragma unroll
            for (int nt = 0; nt < 4; nt++) {
                int col = n0 + wn * 64 + nt * 16 + l15;       // slot index
                u32 bb = __float_as_uint(acc[mt][nt][r]);
                bb = (bb & 0x80000000u) ? ~bb : (bb | 0x80000000u);
                u64 key = ((u64)bb << 32) | (u32)(4095 - col);
                best = best > key ? best : key;
            }
            u64 o;
            o = __shfl_xor(best, 1); best = best > o ? best : o;
            o = __shfl_xor(best, 2); best = best > o ? best : o;
            o = __shfl_xor(best, 4); best = best > o ? best : o;
            o = __shfl_xor(best, 8); best = best > o ? best : o;
            if (l15 == 0) atomicMax(&amax[row], best);
        }
    }
}

// ---------------------------------------------------------------------------
// chains_build v2: decode idx, build per-slot chains. 16 blocks x 64 threads;
// scans over an LDS mirror of all 1024 decoded indices.
__global__ __launch_bounds__(64) void chains_build_kernel(const u64* __restrict__ amax,
                                                          int* __restrict__ idx,
                                                          int* __restrict__ nxt,
                                                          int* __restrict__ heads,
                                                          int* __restrict__ count) {
    __shared__ int sidx[1024];
    int tid = threadIdx.x;
    for (int j = tid; j < 1024; j += 64)
        sidx[j] = 4095 - (int)(u32)(amax[j] & 0xFFFFFFFFull);
    __syncthreads();
    int i = blockIdx.x * 64 + tid;
    int my = sidx[i];
    idx[i] = my;
    int nx = -1;
    for (int j = i + 1; j < 1024; j++)
        if (sidx[j] == my) { nx = j; break; }
    nxt[i] = nx;
    bool head = true;
    for (int j = 0; j < i; j++)
        if (sidx[j] == my) { head = false; break; }
    if (head) {
        int p = atomicAdd(count, 1);
        heads[p] = i;
    }
}

// ---------------------------------------------------------------------------
// G1[i][j] = write_keys[i] . Wg[0:512, j] + bg[j]   (fp32). 8 rows/block, grid=128.
__global__ __launch_bounds__(256) void g1_gemm_kernel(const float* __restrict__ wk,
                                                      const float* __restrict__ Wg,
                                                      const float* __restrict__ bg,
                                                      float* __restrict__ G1) {
    __shared__ float wkl[8][512];
    int tid = threadIdx.x;
    int i0 = blockIdx.x * 8;
    for (int i = tid; i < 8 * 512; i += 256) wkl[i >> 9][i & 511] = wk[(size_t)i0 * 512 + i];
    __syncthreads();
    float a0[8], a1[8];
#pragma unroll
    for (int i = 0; i < 8; i++) { a0[i] = 0.f; a1[i] = 0.f; }
    for (int c = 0; c < 512; c++) {
        float w0 = Wg[(size_t)c * 512 + tid];
        float w1 = Wg[(size_t)c * 512 + tid + 256];
#pragma unroll
        for (int ii = 0; ii < 8; ii++) {
            float s = wkl[ii][c];
            a0[ii] += s * w0; a1[ii] += s * w1;
        }
    }
    float b0 = bg[tid], b1 = bg[tid + 256];
#pragma unroll
    for (int ii = 0; ii < 8; ii++) {
        G1[(size_t)(i0 + ii) * 512 + tid] = a0[ii] + b0;
        G1[(size_t)(i0 + ii) * 512 + tid + 256] = a1[ii] + b1;
    }
}

// ---------------------------------------------------------------------------
// Apply per-slot chains sequentially (fp32). block = 256 threads per chain.
__global__ __launch_bounds__(256) void chain_apply_kernel(const int* __restrict__ heads,
                                                          const int* __restrict__ count,
                                                          const int* __restrict__ idx,
                                                          const int* __restrict__ nxt,
                                                          const float* __restrict__ G1,
                                                          const float* __restrict__ Wg,
                                                          const float* __restrict__ wk,
                                                          const float* __restrict__ wv,
                                                          const float* __restrict__ mk,
                                                          const float* __restrict__ mv,
                                                          float* __restrict__ outK,
                                                          float* __restrict__ outV) {
    int b = blockIdx.x;
    if (b >= *count) return;
    int i = heads[b];
    int s = idx[i];
    int tid = threadIdx.x;
    __shared__ float V[512];
    V[tid] = mv[(size_t)s * 512 + tid];
    V[tid + 256] = mv[(size_t)s * 512 + tid + 256];
    float k0 = mk[(size_t)s * 512 + tid], k1 = mk[(size_t)s * 512 + tid + 256];
    __syncthreads();
    while (i >= 0) {
        float a0 = G1[(size_t)i * 512 + tid], a1 = G1[(size_t)i * 512 + tid + 256];
        for (int c = 0; c < 512; c++) {
            float vc = V[c];
            a0 += vc * Wg[(size_t)(512 + c) * 512 + tid];
            a1 += vc * Wg[(size_t)(512 + c) * 512 + tid + 256];
        }
        float g0 = 1.f / (1.f + __expf(-a0));
        float g1 = 1.f / (1.f + __expf(-a1));
        __syncthreads(); // everyone finished reading V
        k0 = g0 * wk[(size_t)i * 512 + tid] + (1.f - g0) * k0;
        k1 = g1 * wk[(size_t)i * 512 + tid + 256] + (1.f - g1) * k1;
        V[tid] = g0 * wv[(size_t)i * 512 + tid] + (1.f - g0) * V[tid];
        V[tid + 256] = g1 * wv[(size_t)i * 512 + tid + 256] + (1.f - g1) * V[tid + 256];
        __syncthreads();
        i = nxt[i];
    }
    outK[(size_t)s * 512 + tid] = k0;
    outK[(size_t)s * 512 + tid + 256] = k1;
    outV[(size_t)s * 512 + tid] = V[tid];
    outV[(size_t)s * 512 + tid + 256] = V[tid + 256];
}

// ---------------------------------------------------------------------------
extern "C" void kernel_launch(void* const* d_in, const int* in_sizes, int n_in,
                              void* d_out, int out_size, void* d_ws, size_t ws_size,
                              hipStream_t stream) {
    const float* queries = (const float*)d_in[0]; // [4,1024,512]
    const float* wkeys   = (const float*)d_in[1]; // [1024,512]
    const float* wvals   = (const float*)d_in[2]; // [1024,512]
    const float* mkeys   = (const float*)d_in[3]; // [4096,512]
    const float* mvals   = (const float*)d_in[4]; // [4096,512]
    const float* Wq      = (const float*)d_in[5]; // [512,4096]
    const float* bq      = (const float*)d_in[6]; // [4096]
    const float* Wvp     = (const float*)d_in[7]; // [4096,512]
    const float* bvp     = (const float*)d_in[8]; // [512]
    const float* Wg      = (const float*)d_in[9]; // [1024,512]
    const float* bg      = (const float*)d_in[10];// [512]

    float* out_read = (float*)d_out;              // [4,1024,512]
    float* out_k = out_read + (size_t)4 * 1024 * 512; // [4096,512]
    float* out_v = out_k + (size_t)4096 * 512;        // [4096,512]

    char* ws = (char*)d_ws;
    const size_t MB = 1024 * 1024;
    // region [0, 4MB): Qbf during prep/q-proj, then reused for meta + denom
    u16* Qbf  = (u16*)(ws);            // 4 MB   queries bf16 [4096,512]
    u16* WqT  = (u16*)(ws + 4 * MB);   // 4 MB   Wq^T bf16 [4096,512]
    u16* Qatt = (u16*)(ws + 8 * MB);   // 32 MB  q bf16 [(b,h),n,d] = [32768,512]
    u16* Kb   = (u16*)(ws + 40 * MB);  // 4 MB   mem_keys bf16 [4096,512]
    u8*  Vt8  = (u8*)(ws + 44 * MB);   // 2 MB   mem_values^T fp8 [512,4096]
    u16* rv   = (u16*)(ws + 48 * MB);  // 32 MB  attention out bf16 [4096,4096]
    u16* WvpT = (u16*)(ws + 80 * MB);  // 4 MB   Wvp^T bf16 [512,4096]
    // write-path buffers (dead before attention's P overlay):
    u16* mn_hi = (u16*)(ws + 84 * MB); // 4 MB  normalized keys hi bf16 [4096,512]
    u16* mn_lo = (u16*)(ws + 88 * MB); // 4 MB  normalized keys lo bf16 [4096,512]
    float* G1  = (float*)(ws + 92 * MB); // 2 MB gate pre from write_keys [1024,512]
    u16* wk_hi = (u16*)(ws + 94 * MB); // 1 MB  write_keys hi bf16 [1024,512]
    u16* wk_lo = (u16*)(ws + 95 * MB); // 1 MB  write_keys lo bf16 [1024,512]
    // meta + denom overlay the dead Qbf region (valid after q-proj completes)
    u64* amax   = (u64*)(ws);                   // 8 KB
    int* count  = (int*)(ws + 8192);            // 4 B
    int* idx    = (int*)(ws + 8192 + 256);      // 4 KB
    int* nxt    = (int*)(ws + 8192 + 256 + 4096);   // 4 KB
    int* heads  = (int*)(ws + 8192 + 256 + 8192);   // 4 KB
    float* denom = (float*)(ws + 32 * 1024);    // 128 KB [32768]
    // P (fp8) overlays the dead write-path region (valid after chain_apply)
    u8* P = (u8*)(ws + 84 * MB);                // up to 128 MB [G*1024, 4096]
    (void)in_sizes; (void)n_in; (void)out_size;

    // chunk size over bh: P needs G*4MB (fp8) starting at 84MB
    size_t avail = (ws_size > 84 * MB) ? ws_size - 84 * MB : 0;
    int G = 2; // proven-safe floor
    for (int g = 32; g >= 2; g >>= 1)
        if ((size_t)g * 4 * MB <= avail) { G = g; break; }

    // new_keys / new_values start as copies of mem_keys / mem_values
    hipMemcpyAsync(out_k, mkeys, (size_t)4096 * 512 * 4, hipMemcpyDeviceToDevice, stream);
    hipMemcpyAsync(out_v, mvals, (size_t)4096 * 512 * 4, hipMemcpyDeviceToDevice, stream);

    // ---- prep casts / transposes ----
    cast_bf16_kernel<<<2048, 256, 0, stream>>>(queries, Qbf);
    cast_transpose_kernel<<<dim3(4096 / 32, 512 / 32), 256, 0, stream>>>(Wq, WqT, 512, 4096);
    cast_transpose_kernel<<<dim3(512 / 32, 4096 / 32), 256, 0, stream>>>(Wvp, WvpT, 4096, 512);
    cast_transpose_fp8_kernel<<<dim3(512 / 32, 4096 / 32), 256, 0, stream>>>(mvals, Vt8, 4096, 512);
    key_prep_kernel<<<4096, 256, 0, stream>>>(mkeys, mn_hi, mn_lo, Kb);
    split_bf16_kernel<<<512, 256, 0, stream>>>(wkeys, wk_hi, wk_lo);

    // ---- q-proj (last user of Qbf/WqT) ----
    gemm_bt_kernel<128, 1><<<dim3(32, 32), 256, 0, stream>>>(Qbf, WqT, bq, (void*)Qatt, 4096, 4096, 512);

    // ---- write path (fp32-accurate), frees buffers for the P overlay after ----
    hipMemsetAsync(ws, 0, 8192 + 256, stream);          // amax + count (Qbf now dead)
    hipMemsetAsync(denom, 0, 32768 * 4, stream);        // denom
    sims_mfma_kernel<<<dim3(32, 8), 256, 0, stream>>>(wk_hi, wk_lo, mn_hi, mn_lo, amax);
    chains_build_kernel<<<16, 64, 0, stream>>>(amax, idx, nxt, heads, count);
    g1_gemm_kernel<<<128, 256, 0, stream>>>(wkeys, Wg, bg, G1);
    chain_apply_kernel<<<1024, 256, 0, stream>>>(heads, count, idx, nxt, G1, Wg,
                                                 wkeys, wvals, mkeys, mvals, out_k, out_v);

    // ---- attention as two GEMM passes (P in fp8), chunked over bh ----
    for (int bh0 = 0; bh0 < 32; bh0 += G) {
        const u16* Achunk = Qatt + (size_t)bh0 * 1024 * 512;
        float* dchunk = denom + bh0 * 1024;
        s_exp_gemm_kernel<<<dim3(32, G * 8), 256, 0, stream>>>(Achunk, Kb, P, dchunk);
        pv_gemm_kernel<<<dim3(4, G * 8), 256, 0, stream>>>(P, Vt8, dchunk, rv, bh0);
    }

    // ---- out-proj: BM=64 tile, 2 blocks/CU ----
    gemm_bt_m64_kernel<<<dim3(8, 64), 256, 0, stream>>>(rv, WvpT, bvp, out_read, 4096, 512, 4096);
}